// Round 2
// baseline (1191.776 us; speedup 1.0000x reference)
//
#include <hip/hip_runtime.h>
#include <cstddef>

#define NSEQ   1025
#define NBATCH 8
#define NTOK   8200      // 8*1025
#define DIMX   768
#define NHEADS 12
#define DHEAD  64

// ---------------- LayerNorm: one block per token ----------------
__launch_bounds__(256)
__global__ void ln_kernel(const float* __restrict__ x, const float* __restrict__ g,
                          const float* __restrict__ bb, float* __restrict__ xn)
{
    int t = blockIdx.x;
    int tid = threadIdx.x;
    const float* xp = x + (size_t)t * DIMX;
    float v0 = xp[tid], v1 = xp[tid + 256], v2 = xp[tid + 512];
    float s  = v0 + v1 + v2;
    float ss = v0*v0 + v1*v1 + v2*v2;
    for (int off = 32; off > 0; off >>= 1) {
        s  += __shfl_down(s,  off, 64);
        ss += __shfl_down(ss, off, 64);
    }
    __shared__ float red[8];
    __shared__ float stats[2];
    int w = tid >> 6, lane = tid & 63;
    if (lane == 0) { red[w] = s; red[4 + w] = ss; }
    __syncthreads();
    if (tid == 0) {
        float S  = red[0] + red[1] + red[2] + red[3];
        float SS = red[4] + red[5] + red[6] + red[7];
        float mu  = S * (1.0f / DIMX);
        float var = SS * (1.0f / DIMX) - mu * mu;
        stats[0] = mu;
        stats[1] = rsqrtf(var + 1e-5f);
    }
    __syncthreads();
    float mu = stats[0], rs = stats[1];
    float* op = xn + (size_t)t * DIMX;
    op[tid]       = (v0 - mu) * rs * g[tid]       + bb[tid];
    op[tid + 256] = (v1 - mu) * rs * g[tid + 256] + bb[tid + 256];
    op[tid + 512] = (v2 - mu) * rs * g[tid + 512] + bb[tid + 512];
}

// ---------------- cls token -> q (head layout) ----------------
__global__ void cls_q_kernel(const float* __restrict__ xn, float* __restrict__ q)
{
    int b = blockIdx.x;
    for (int c = threadIdx.x; c < DIMX; c += 256) {
        float val = xn[(size_t)b * NSEQ * DIMX + c];
        // n = 0
        q[((size_t)(b * NHEADS + (c >> 6)) * NSEQ) * DHEAD + (c & 63)] = val;
    }
}

// ---------------- transpose dw weights (768,25) -> (25,768) ----------------
__global__ void dwt_kernel(const float* __restrict__ w, float* __restrict__ wt)
{
    int idx = blockIdx.x * 256 + threadIdx.x;
    if (idx >= 768 * 25) return;
    int c = idx / 25, wi = idx % 25;
    wt[wi * 768 + c] = w[idx];
}

// ---------------- depthwise 5x5 conv, channel-last ----------------
__launch_bounds__(256)
__global__ void dw_kernel(const float* __restrict__ xn, const float* __restrict__ wt,
                          float* __restrict__ out)
{
    int pix = blockIdx.x;           // b*1024 + y*32 + x
    int b = pix >> 10, p = pix & 1023, y = p >> 5, xx0 = p & 31;
    int c = threadIdx.x;
    float a0 = 0.f, a1 = 0.f, a2 = 0.f;
    for (int dy = 0; dy < 5; dy++) {
        int yy = y + dy - 2;
        if ((unsigned)yy >= 32u) continue;
        for (int dx = 0; dx < 5; dx++) {
            int xx = xx0 + dx - 2;
            if ((unsigned)xx >= 32u) continue;
            const float* ip = xn + ((size_t)(b * NSEQ) + 1 + yy * 32 + xx) * DIMX;
            const float* wp = wt + (dy * 5 + dx) * DIMX;
            a0 += ip[c]       * wp[c];
            a1 += ip[c + 256] * wp[c + 256];
            a2 += ip[c + 512] * wp[c + 512];
        }
    }
    float* op = out + (size_t)pix * DIMX;
    op[c] = a0; op[c + 256] = a1; op[c + 512] = a2;
}

// ---------------- transpose pw_w (768x768) ----------------
__global__ void transpose768(const float* __restrict__ in, float* __restrict__ out)
{
    __shared__ float tile[32][33];
    int x  = blockIdx.x * 32 + threadIdx.x;
    int y0 = blockIdx.y * 32;
    for (int i = threadIdx.y; i < 32; i += 8)
        tile[i][threadIdx.x] = in[(size_t)(y0 + i) * 768 + x];
    __syncthreads();
    int xo  = blockIdx.y * 32 + threadIdx.x;
    int yo0 = blockIdx.x * 32;
    for (int i = threadIdx.y; i < 32; i += 8)
        out[(size_t)(yo0 + i) * 768 + xo] = tile[threadIdx.x][i];
}

// ---------------- generic fp32 GEMM, K=768, 64x64 tile ----------------
// MODE 0: kv  -> split cols into K (O0) / V (O1), head-scatter, M=8200, Ncol=1536
// MODE 1: pw  -> q head-scatter (n = pix+1),                    M=8192, Ncol=768
// MODE 2: out -> O0[r*768+c] = acc + bias[c],                   M=8200, Ncol=768
template<int MODE>
__launch_bounds__(256)
__global__ void gemm_k768(const float* __restrict__ A, const float* __restrict__ Bm,
                          const float* __restrict__ bias, float* __restrict__ O0,
                          float* __restrict__ O1, int M, int Ncol)
{
    __shared__ float As[16][68];
    __shared__ float Bs[16][68];
    const int tid = threadIdx.x;
    const int r0 = blockIdx.y * 64, c0 = blockIdx.x * 64;
    const int ty = tid >> 4, tx = tid & 15;
    const int lar = tid >> 2, lak = (tid & 3) * 4;
    const int lbk = tid >> 4, lbc = (tid & 15) * 4;
    float acc[4][4] = {};
    for (int k0 = 0; k0 < 768; k0 += 16) {
        float4 av = make_float4(0.f, 0.f, 0.f, 0.f);
        if (r0 + lar < M) av = *(const float4*)(A + (size_t)(r0 + lar) * 768 + k0 + lak);
        float4 bv = *(const float4*)(Bm + (size_t)(k0 + lbk) * Ncol + c0 + lbc);
        __syncthreads();
        As[lak + 0][lar] = av.x; As[lak + 1][lar] = av.y;
        As[lak + 2][lar] = av.z; As[lak + 3][lar] = av.w;
        *(float4*)&Bs[lbk][lbc] = bv;
        __syncthreads();
        #pragma unroll
        for (int kk = 0; kk < 16; kk++) {
            float4 a  = *(float4*)&As[kk][ty * 4];
            float4 bq = *(float4*)&Bs[kk][tx * 4];
            float ar[4] = {a.x, a.y, a.z, a.w};
            float br[4] = {bq.x, bq.y, bq.z, bq.w};
            #pragma unroll
            for (int i = 0; i < 4; i++)
                #pragma unroll
                for (int j = 0; j < 4; j++)
                    acc[i][j] += ar[i] * br[j];
        }
    }
    #pragma unroll
    for (int i = 0; i < 4; i++) {
        int r = r0 + ty * 4 + i;
        if (r >= M) continue;
        if (MODE == 0) {
            int b = r / NSEQ, n = r % NSEQ;
            #pragma unroll
            for (int j = 0; j < 4; j++) {
                int c = c0 + tx * 4 + j;
                // NOTE: 768 is NOT pow2 — must subtract, not mask (c & 767 was the R1 bug)
                int cc = (c < 768) ? c : c - 768;
                float* dst = (c < 768) ? O0 : O1;
                dst[((size_t)(b * NHEADS + (cc >> 6)) * NSEQ + n) * DHEAD + (cc & 63)] = acc[i][j];
            }
        } else if (MODE == 1) {
            int b = r >> 10, pix = r & 1023, n = pix + 1;
            #pragma unroll
            for (int j = 0; j < 4; j++) {
                int c = c0 + tx * 4 + j;
                O0[((size_t)(b * NHEADS + (c >> 6)) * NSEQ + n) * DHEAD + (c & 63)] = acc[i][j];
            }
        } else {
            #pragma unroll
            for (int j = 0; j < 4; j++) {
                int c = c0 + tx * 4 + j;
                O0[(size_t)r * 768 + c] = acc[i][j] + bias[c];
            }
        }
    }
}

// ---------------- RoPE on q and k (first 32 dims/head, n>=1) ----------------
__launch_bounds__(256)
__global__ void rope_kernel(float* __restrict__ q, float* __restrict__ k,
                            const float* __restrict__ sinb, const float* __restrict__ cosb)
{
    int idx = blockIdx.x * 256 + threadIdx.x;   // < 96*1024*16
    int pr  = idx & 15;
    int pos = (idx >> 4) & 1023;
    int bh  = idx >> 14;
    float c0 = cosb[pos * 32 + pr * 2], c1 = cosb[pos * 32 + pr * 2 + 1];
    float s0 = sinb[pos * 32 + pr * 2], s1 = sinb[pos * 32 + pr * 2 + 1];
    size_t base = ((size_t)bh * NSEQ + 1 + pos) * DHEAD + pr * 2;
    float2 qv = *(float2*)(q + base);
    float2 kv = *(float2*)(k + base);
    float2 qo, ko;
    qo.x = qv.x * c0 - qv.y * s0;  qo.y = qv.y * c1 + qv.x * s1;
    ko.x = kv.x * c0 - kv.y * s0;  ko.y = kv.y * c1 + kv.x * s1;
    *(float2*)(q + base) = qo;
    *(float2*)(k + base) = ko;
}

// ---------------- flash attention fp32: 64-row Q tile per block ----------------
__launch_bounds__(256)
__global__ void attn_kernel(const float* __restrict__ q, const float* __restrict__ k,
                            const float* __restrict__ v, float* __restrict__ o)
{
    __shared__ float QsT[64][68];   // [d][row]
    __shared__ float KPs[64][68];   // K as [d][j], then P as [j][row]
    __shared__ float Vs [64][68];   // [j][d]
    const int tid = threadIdx.x;
    const int i0  = blockIdx.x * 64;
    const int bh  = blockIdx.y;
    const int b = bh / NHEADS, h = bh % NHEADS;
    const size_t qkv_base = (size_t)bh * NSEQ * DHEAD;

    {   // load Q tile transposed
        int jj = tid >> 2, lq = tid & 3;
        int row = i0 + jj;
        for (int qq = lq; qq < 16; qq += 4) {
            float4 val = make_float4(0.f, 0.f, 0.f, 0.f);
            if (row < NSEQ) val = *(const float4*)(q + qkv_base + (size_t)row * DHEAD + qq * 4);
            QsT[qq * 4 + 0][jj] = val.x; QsT[qq * 4 + 1][jj] = val.y;
            QsT[qq * 4 + 2][jj] = val.z; QsT[qq * 4 + 3][jj] = val.w;
        }
    }

    const int rg = tid >> 4, jg = tid & 15;
    const int r4 = rg * 4, c4 = jg * 4;
    float acc[4][4] = {};
    float m[4] = {-1e30f, -1e30f, -1e30f, -1e30f};
    float l[4] = {0.f, 0.f, 0.f, 0.f};

    for (int t = 0; t < 17; t++) {
        const int j0 = t * 64;
        __syncthreads();                      // prev tile's PV reads done
        {   // load K transposed + V direct (zero-fill masked rows)
            int jj = tid >> 2, lq = tid & 3;
            int row = j0 + jj;
            bool ok = row < NSEQ;
            const float* kp = k + qkv_base + (size_t)row * DHEAD;
            const float* vp = v + qkv_base + (size_t)row * DHEAD;
            for (int qq = lq; qq < 16; qq += 4) {
                float4 kv4 = make_float4(0.f,0.f,0.f,0.f), vv4 = make_float4(0.f,0.f,0.f,0.f);
                if (ok) { kv4 = *(const float4*)(kp + qq * 4); vv4 = *(const float4*)(vp + qq * 4); }
                KPs[qq * 4 + 0][jj] = kv4.x; KPs[qq * 4 + 1][jj] = kv4.y;
                KPs[qq * 4 + 2][jj] = kv4.z; KPs[qq * 4 + 3][jj] = kv4.w;
                *(float4*)&Vs[jj][qq * 4] = vv4;
            }
        }
        __syncthreads();
        // S = Q K^T  (thread: 4 rows x 4 cols)
        float s[4][4] = {};
        #pragma unroll 8
        for (int kk = 0; kk < 64; kk++) {
            float4 a  = *(float4*)&QsT[kk][r4];
            float4 bq = *(float4*)&KPs[kk][c4];
            float ar[4] = {a.x, a.y, a.z, a.w};
            float br[4] = {bq.x, bq.y, bq.z, bq.w};
            #pragma unroll
            for (int i = 0; i < 4; i++)
                #pragma unroll
                for (int j = 0; j < 4; j++)
                    s[i][j] += ar[i] * br[j];
        }
        #pragma unroll
        for (int ri = 0; ri < 4; ri++)
            #pragma unroll
            for (int jj = 0; jj < 4; jj++) {
                int j = j0 + c4 + jj;
                s[ri][jj] = (j < NSEQ) ? s[ri][jj] * 0.125f : -1e30f;
            }
        // online softmax update
        #pragma unroll
        for (int ri = 0; ri < 4; ri++) {
            float tmax = fmaxf(fmaxf(s[ri][0], s[ri][1]), fmaxf(s[ri][2], s[ri][3]));
            for (int off = 1; off < 16; off <<= 1) tmax = fmaxf(tmax, __shfl_xor(tmax, off, 64));
            float mnew  = fmaxf(m[ri], tmax);
            float alpha = __expf(m[ri] - mnew);
            float rsum = 0.f;
            #pragma unroll
            for (int jj = 0; jj < 4; jj++) {
                float p = __expf(s[ri][jj] - mnew);
                s[ri][jj] = p; rsum += p;
            }
            for (int off = 1; off < 16; off <<= 1) rsum += __shfl_xor(rsum, off, 64);
            m[ri] = mnew;
            l[ri] = l[ri] * alpha + rsum;
            #pragma unroll
            for (int ci = 0; ci < 4; ci++) acc[ri][ci] *= alpha;
        }
        __syncthreads();                      // all threads done reading KPs as K
        #pragma unroll
        for (int ri = 0; ri < 4; ri++)
            #pragma unroll
            for (int jj = 0; jj < 4; jj++)
                KPs[c4 + jj][r4 + ri] = s[ri][jj];   // P as [j][row]
        __syncthreads();
        // PV accumulate
        #pragma unroll 8
        for (int j = 0; j < 64; j++) {
            float4 p4 = *(float4*)&KPs[j][r4];
            float4 vv = *(float4*)&Vs[j][c4];
            float pr[4] = {p4.x, p4.y, p4.z, p4.w};
            float vr[4] = {vv.x, vv.y, vv.z, vv.w};
            #pragma unroll
            for (int ri = 0; ri < 4; ri++)
                #pragma unroll
                for (int ci = 0; ci < 4; ci++)
                    acc[ri][ci] += pr[ri] * vr[ci];
        }
    }
    #pragma unroll
    for (int ri = 0; ri < 4; ri++) {
        int row = i0 + r4 + ri;
        if (row >= NSEQ) continue;
        float inv = 1.0f / l[ri];
        float* op = o + ((size_t)b * NSEQ + row) * DIMX + h * DHEAD + c4;
        op[0] = acc[ri][0] * inv; op[1] = acc[ri][1] * inv;
        op[2] = acc[ri][2] * inv; op[3] = acc[ri][3] * inv;
    }
}

extern "C" void kernel_launch(void* const* d_in, const int* in_sizes, int n_in,
                              void* d_out, int out_size, void* d_ws, size_t ws_size,
                              hipStream_t stream)
{
    const float* x     = (const float*)d_in[0];
    const float* sinb  = (const float*)d_in[1];
    const float* cosb  = (const float*)d_in[2];
    const float* ln_g  = (const float*)d_in[3];
    const float* ln_b  = (const float*)d_in[4];
    const float* dw_w  = (const float*)d_in[5];
    const float* pw_w  = (const float*)d_in[6];
    const float* kv_w  = (const float*)d_in[7];
    const float* out_w = (const float*)d_in[8];
    const float* out_b = (const float*)d_in[9];
    (void)in_sizes; (void)n_in; (void)out_size; (void)ws_size;

    float* ws    = (float*)d_ws;
    float* xn    = ws;                 // 6,297,600  (later reused as attn output)
    float* dwout = ws + 6297600;       // 6,297,600  (later reused as K)
    float* qb    = ws + 12595200;      // 6,297,600
    float* vb    = ws + 18892800;      // 6,297,600
    float* pwT   = ws + 25190400;      // 589,824
    float* dwT   = ws + 25780224;      // 19,200     -> total 25,799,424 fl = 103.2 MB
    float* kb     = dwout;             // kv GEMM runs after pw GEMM consumed dwout
    float* attn_o = xn;                // attention runs after xn is dead

    ln_kernel   <<<NTOK, 256, 0, stream>>>(x, ln_g, ln_b, xn);
    cls_q_kernel<<<NBATCH, 256, 0, stream>>>(xn, qb);
    dwt_kernel  <<<75, 256, 0, stream>>>(dw_w, dwT);
    dw_kernel   <<<NBATCH * 1024, 256, 0, stream>>>(xn, dwT, dwout);
    transpose768<<<dim3(24, 24), dim3(32, 8), 0, stream>>>(pw_w, pwT);
    gemm_k768<1><<<dim3(12, 128), 256, 0, stream>>>(dwout, pwT, nullptr, qb, nullptr, 8192, 768);
    gemm_k768<0><<<dim3(24, 129), 256, 0, stream>>>(xn, kv_w, nullptr, kb, vb, NTOK, 1536);
    rope_kernel <<<6144, 256, 0, stream>>>(qb, kb, sinb, cosb);
    attn_kernel <<<dim3(17, 96), 256, 0, stream>>>(qb, kb, vb, attn_o);
    gemm_k768<2><<<dim3(12, 129), 256, 0, stream>>>(attn_o, out_w, out_b, (float*)d_out, nullptr, NTOK, 768);
}

// Round 4
// 465.892 us; speedup vs baseline: 2.5580x; 2.5580x over previous
//
#include <hip/hip_runtime.h>
#include <cstddef>

#define NSEQ   1025
#define NBATCH 8
#define NTOK   8200      // 8*1025
#define DIMX   768
#define NHEADS 12
#define DHEAD  64
#define VTP    1040      // Vt row pitch (bf16), 16B-aligned (1040*2=2080=130*16)
#define LDP    72        // LDS row pitch (bf16) for 64-wide K tiles: 144B rows, 2-way-conflict-free

typedef short bf16x8 __attribute__((ext_vector_type(8)));   // per guide §3 (compile-verified on gfx950)
typedef float f32x4  __attribute__((ext_vector_type(4)));
typedef unsigned short u16;

__device__ __forceinline__ float bf2f(u16 u) {
    unsigned v = (unsigned)u << 16; float f; __builtin_memcpy(&f, &v, 4); return f;
}
__device__ __forceinline__ u16 f2bf(float f) {
    unsigned u; __builtin_memcpy(&u, &f, 4);
    return (u16)((u + 0x7FFFu + ((u >> 16) & 1u)) >> 16);   // RNE
}

// ---------------- LayerNorm: one block per token, bf16 out ----------------
__launch_bounds__(256)
__global__ void ln_kernel(const float* __restrict__ x, const float* __restrict__ g,
                          const float* __restrict__ bb, u16* __restrict__ xn)
{
    int t = blockIdx.x, tid = threadIdx.x;
    const float* xp = x + (size_t)t * DIMX;
    float v0 = xp[tid], v1 = xp[tid + 256], v2 = xp[tid + 512];
    float s  = v0 + v1 + v2;
    float ss = v0*v0 + v1*v1 + v2*v2;
    for (int off = 32; off > 0; off >>= 1) {
        s  += __shfl_down(s,  off, 64);
        ss += __shfl_down(ss, off, 64);
    }
    __shared__ float red[8];
    __shared__ float stats[2];
    int w = tid >> 6, lane = tid & 63;
    if (lane == 0) { red[w] = s; red[4 + w] = ss; }
    __syncthreads();
    if (tid == 0) {
        float S  = red[0] + red[1] + red[2] + red[3];
        float SS = red[4] + red[5] + red[6] + red[7];
        float mu  = S * (1.0f / DIMX);
        float var = SS * (1.0f / DIMX) - mu * mu;
        stats[0] = mu; stats[1] = rsqrtf(var + 1e-5f);
    }
    __syncthreads();
    float mu = stats[0], rs = stats[1];
    u16* op = xn + (size_t)t * DIMX;
    op[tid]       = f2bf((v0 - mu) * rs * g[tid]       + bb[tid]);
    op[tid + 256] = f2bf((v1 - mu) * rs * g[tid + 256] + bb[tid + 256]);
    op[tid + 512] = f2bf((v2 - mu) * rs * g[tid + 512] + bb[tid + 512]);
}

// ---------------- cls token -> q row 0 (head layout, bf16 passthrough) ----------------
__global__ void cls_q_kernel(const u16* __restrict__ xn, u16* __restrict__ q)
{
    int b = blockIdx.x;
    for (int c = threadIdx.x; c < DIMX; c += 256)
        q[((size_t)(b * NHEADS + (c >> 6)) * NSEQ) * DHEAD + (c & 63)] = xn[(size_t)b * NSEQ * DIMX + c];
}

// ---------------- transpose dw weights (768,25) -> (25,768) fp32 ----------------
__global__ void dwt_kernel(const float* __restrict__ w, float* __restrict__ wt)
{
    int idx = blockIdx.x * 256 + threadIdx.x;
    if (idx >= 768 * 25) return;
    int c = idx / 25, wi = idx % 25;
    wt[wi * 768 + c] = w[idx];
}

// ---------------- fp32 -> bf16 convert ----------------
__global__ void convert_kernel(const float* __restrict__ in, u16* __restrict__ out)
{
    int i = blockIdx.x * 256 + threadIdx.x;
    out[i] = f2bf(in[i]);
}

// ---------------- transpose fp32 [R][C] -> bf16 [C][R] (R,C mult of 32) ----------------
__global__ void transpose_f2b(const float* __restrict__ in, u16* __restrict__ out, int R, int C)
{
    __shared__ float tile[32][33];
    int x  = blockIdx.x * 32 + threadIdx.x;
    int y0 = blockIdx.y * 32;
    for (int i = threadIdx.y; i < 32; i += 8)
        tile[i][threadIdx.x] = in[(size_t)(y0 + i) * C + x];
    __syncthreads();
    int xo  = blockIdx.y * 32 + threadIdx.x;
    int yo0 = blockIdx.x * 32;
    for (int i = threadIdx.y; i < 32; i += 8)
        out[(size_t)(yo0 + i) * R + xo] = f2bf(tile[threadIdx.x][i]);
}

// ---------------- depthwise 5x5 conv, bf16 in/out, fp32 math ----------------
__launch_bounds__(256)
__global__ void dw_kernel(const u16* __restrict__ xn, const float* __restrict__ wt,
                          u16* __restrict__ out)
{
    int pix = blockIdx.x;           // b*1024 + y*32 + x
    int b = pix >> 10, p = pix & 1023, y = p >> 5, xx0 = p & 31;
    int c = threadIdx.x;
    float a0 = 0.f, a1 = 0.f, a2 = 0.f;
    for (int dy = 0; dy < 5; dy++) {
        int yy = y + dy - 2;
        if ((unsigned)yy >= 32u) continue;
        for (int dx = 0; dx < 5; dx++) {
            int xx = xx0 + dx - 2;
            if ((unsigned)xx >= 32u) continue;
            const u16*   ip = xn + ((size_t)(b * NSEQ) + 1 + yy * 32 + xx) * DIMX;
            const float* wp = wt + (dy * 5 + dx) * DIMX;
            a0 += bf2f(ip[c])       * wp[c];
            a1 += bf2f(ip[c + 256]) * wp[c + 256];
            a2 += bf2f(ip[c + 512]) * wp[c + 512];
        }
    }
    u16* op = out + (size_t)pix * DIMX;
    op[c] = f2bf(a0); op[c + 256] = f2bf(a1); op[c + 512] = f2bf(a2);
}

// ---------------- bf16 MFMA GEMM: C[M][N] = A[M][768] * Bn^T, Bn = [N][768] (k-major) ----
// 128x128 tile, BK=64, 4 waves (2x2), each wave 64x64 via 16 16x16x32 MFMAs per k-step.
// MODE 0: kv  -> K/V bf16 head-scatter (N=1536)   MODE 1: pw -> q bf16 head-scatter (n=pix+1)
// MODE 2: out -> fp32 d_out + bias (N=768)
template<int MODE>
__launch_bounds__(256)
__global__ void gemm_bf16(const u16* __restrict__ A, const u16* __restrict__ Bn,
                          const float* __restrict__ bias, u16* __restrict__ Ob0,
                          u16* __restrict__ Ob1, float* __restrict__ Of, int M)
{
    __shared__ u16 As[128 * LDP];
    __shared__ u16 Bs[128 * LDP];
    const int tid  = threadIdx.x;
    const int wave = tid >> 6, lane = tid & 63;
    const int q8 = lane >> 4, cc = lane & 15;
    const int wr = wave >> 1, wc = wave & 1;
    const long r0 = (long)blockIdx.y * 128;
    const int  c0 = blockIdx.x * 128;

    f32x4 acc[4][4] = {};

    for (int k0 = 0; k0 < 768; k0 += 64) {
        // 128 rows x 64 bf16 = 1024 16B-chunks per tile -> 4 passes of 256 threads
        // (R3 NaN root cause: 2 passes staged only rows 0-63; rows 64-127 were uninit LDS)
        uint4 areg[4], breg[4];
        #pragma unroll
        for (int pass = 0; pass < 4; pass++) {
            int ci = tid + pass * 256;
            int row = ci >> 3, ch = ci & 7;
            long ar = r0 + row;
            areg[pass] = (ar < M) ? *(const uint4*)(A + ar * 768 + k0 + ch * 8)
                                  : make_uint4(0, 0, 0, 0);
            breg[pass] = *(const uint4*)(Bn + (size_t)(c0 + row) * 768 + k0 + ch * 8);
        }
        __syncthreads();
        #pragma unroll
        for (int pass = 0; pass < 4; pass++) {
            int ci = tid + pass * 256;
            int row = ci >> 3, ch = ci & 7;
            *(uint4*)(As + row * LDP + ch * 8) = areg[pass];
            *(uint4*)(Bs + row * LDP + ch * 8) = breg[pass];
        }
        __syncthreads();
        #pragma unroll
        for (int ks = 0; ks < 2; ks++) {
            bf16x8 af[4], bfr[4];
            #pragma unroll
            for (int mi = 0; mi < 4; mi++)
                af[mi] = *(const bf16x8*)(As + (wr * 64 + mi * 16 + cc) * LDP + ks * 32 + q8 * 8);
            #pragma unroll
            for (int ni = 0; ni < 4; ni++)
                bfr[ni] = *(const bf16x8*)(Bs + (wc * 64 + ni * 16 + cc) * LDP + ks * 32 + q8 * 8);
            #pragma unroll
            for (int mi = 0; mi < 4; mi++)
                #pragma unroll
                for (int ni = 0; ni < 4; ni++)
                    acc[mi][ni] = __builtin_amdgcn_mfma_f32_16x16x32_bf16(af[mi], bfr[ni], acc[mi][ni], 0, 0, 0);
        }
    }
    // epilogue: element (mi,ni,reg): row = r0+wr*64+mi*16+q8*4+reg, col = c0+wc*64+ni*16+cc
    #pragma unroll
    for (int mi = 0; mi < 4; mi++) {
        #pragma unroll
        for (int r = 0; r < 4; r++) {
            long row = r0 + wr * 64 + mi * 16 + q8 * 4 + r;
            if (row >= M) continue;
            int b, n;
            if (MODE == 1) { b = (int)(row >> 10); n = (int)(row & 1023) + 1; }
            else           { b = (int)(row / NSEQ); n = (int)(row % NSEQ); }
            #pragma unroll
            for (int ni = 0; ni < 4; ni++) {
                int col = c0 + wc * 64 + ni * 16 + cc;
                float val = acc[mi][ni][r];
                if (MODE == 0) {
                    if (col < 768)
                        Ob0[((size_t)(b * NHEADS + (col >> 6)) * NSEQ + n) * DHEAD + (col & 63)] = f2bf(val);
                    else {
                        int c2 = col - 768;   // 768 not pow2 — subtract, don't mask
                        Ob1[((size_t)(b * NHEADS + (c2 >> 6)) * NSEQ + n) * DHEAD + (c2 & 63)] = f2bf(val);
                    }
                } else if (MODE == 1) {
                    Ob0[((size_t)(b * NHEADS + (col >> 6)) * NSEQ + n) * DHEAD + (col & 63)] = f2bf(val);
                } else {
                    Of[(size_t)row * 768 + col] = val + bias[col];
                }
            }
        }
    }
}

// ---------------- RoPE on bf16 q,k (first 32 dims/head, n>=1) ----------------
__launch_bounds__(256)
__global__ void rope_kernel(u16* __restrict__ q, u16* __restrict__ k,
                            const float* __restrict__ sinb, const float* __restrict__ cosb)
{
    int idx = blockIdx.x * 256 + threadIdx.x;   // < 96*1024*16
    int pr  = idx & 15;
    int pos = (idx >> 4) & 1023;
    int bh  = idx >> 14;
    float c0 = cosb[pos * 32 + pr * 2], c1 = cosb[pos * 32 + pr * 2 + 1];
    float s0 = sinb[pos * 32 + pr * 2], s1 = sinb[pos * 32 + pr * 2 + 1];
    size_t base = ((size_t)bh * NSEQ + 1 + pos) * DHEAD + pr * 2;
    float q0 = bf2f(q[base]), q1 = bf2f(q[base + 1]);
    float k0 = bf2f(k[base]), k1 = bf2f(k[base + 1]);
    q[base]     = f2bf(q0 * c0 - q1 * s0);
    q[base + 1] = f2bf(q1 * c1 + q0 * s1);
    k[base]     = f2bf(k0 * c0 - k1 * s0);
    k[base + 1] = f2bf(k1 * c1 + k0 * s1);
}

// ---------------- V [bh][1025][64] -> Vt [bh][64][VTP] (zero pad) ----------------
__global__ void vt_kernel(const u16* __restrict__ v, u16* __restrict__ Vt)
{
    __shared__ u16 tile[32][33];
    int bh = blockIdx.z;
    int n0 = blockIdx.x * 32, d0 = blockIdx.y * 32;
    for (int i = threadIdx.y; i < 32; i += 8) {
        int n = n0 + i;
        tile[i][threadIdx.x] = (n < NSEQ) ? v[((size_t)bh * NSEQ + n) * 64 + d0 + threadIdx.x] : (u16)0;
    }
    __syncthreads();
    for (int i = threadIdx.y; i < 32; i += 8) {
        int n = n0 + threadIdx.x;
        if (n < VTP) Vt[((size_t)bh * 64 + d0 + i) * VTP + n] = tile[threadIdx.x][i];
    }
}

// ---------------- flash attention, bf16 MFMA: 64-row Q tile, 4 waves x 16 rows ----------
__launch_bounds__(256)
__global__ void attn_kernel(const u16* __restrict__ q, const u16* __restrict__ k,
                            const u16* __restrict__ Vt, u16* __restrict__ o)
{
    __shared__ u16 Qs[64 * LDP];
    __shared__ u16 Ks[64 * LDP];
    __shared__ u16 Vs[64 * LDP];      // V^T tile: [d][j]
    __shared__ u16 Ps[4 * 16 * LDP];  // per-wave P tile: [row][j]
    const int tid  = threadIdx.x;
    const int wave = tid >> 6, lane = tid & 63;
    const int q8 = lane >> 4, cc = lane & 15;
    const int i0 = blockIdx.x * 64;
    const int bh = blockIdx.y;
    const int b = bh / NHEADS, h = bh % NHEADS;
    const size_t kqbase = (size_t)bh * NSEQ * 64;
    const size_t vtbase = (size_t)bh * 64 * VTP;

    // stage Q tile (zero-fill rows >= NSEQ); 64x64 tile = 512 chunks = 2 passes
    #pragma unroll
    for (int pass = 0; pass < 2; pass++) {
        int ci = tid + pass * 256;
        int row = ci >> 3, ch = ci & 7;
        uint4 val = make_uint4(0, 0, 0, 0);
        if (i0 + row < NSEQ) val = *(const uint4*)(q + kqbase + (size_t)(i0 + row) * 64 + ch * 8);
        *(uint4*)(Qs + row * LDP + ch * 8) = val;
    }

    f32x4 O[4] = {};
    float mrow[4] = {-1e30f, -1e30f, -1e30f, -1e30f};
    float lrow[4] = {0.f, 0.f, 0.f, 0.f};
    u16* Psw = Ps + wave * 16 * LDP;

    for (int jt = 0; jt < 17; jt++) {
        int j0 = jt * 64;
        __syncthreads();                       // prev iter's K/V reads done (covers Q 1st iter)
        #pragma unroll
        for (int pass = 0; pass < 2; pass++) {
            int ci = tid + pass * 256;
            int row = ci >> 3, ch = ci & 7;
            uint4 kv4 = make_uint4(0, 0, 0, 0);
            if (j0 + row < NSEQ) kv4 = *(const uint4*)(k + kqbase + (size_t)(j0 + row) * 64 + ch * 8);
            *(uint4*)(Ks + row * LDP + ch * 8) = kv4;
            uint4 vv4 = make_uint4(0, 0, 0, 0);
            if (j0 + ch * 8 < VTP) vv4 = *(const uint4*)(Vt + vtbase + (size_t)row * VTP + j0 + ch * 8);
            *(uint4*)(Vs + row * LDP + ch * 8) = vv4;
        }
        __syncthreads();

        // S = Q K^T : wave's 16 rows x 64 cols in 4 frags
        f32x4 sf[4] = {};
        #pragma unroll
        for (int ks = 0; ks < 2; ks++) {
            bf16x8 aq = *(const bf16x8*)(Qs + (wave * 16 + cc) * LDP + ks * 32 + q8 * 8);
            #pragma unroll
            for (int ni = 0; ni < 4; ni++) {
                bf16x8 bk = *(const bf16x8*)(Ks + (ni * 16 + cc) * LDP + ks * 32 + q8 * 8);
                sf[ni] = __builtin_amdgcn_mfma_f32_16x16x32_bf16(aq, bk, sf[ni], 0, 0, 0);
            }
        }

        // scale + mask + online softmax (row = q8*4 + r, cols across cc within quad)
        float p[4][4];      // [ni][r]
        float alpha[4];
        #pragma unroll
        for (int r = 0; r < 4; r++) {
            float tmax = -1e30f;
            #pragma unroll
            for (int ni = 0; ni < 4; ni++) {
                int j = j0 + ni * 16 + cc;
                float s = (j < NSEQ) ? sf[ni][r] * 0.125f : -1e30f;
                p[ni][r] = s;
                tmax = fmaxf(tmax, s);
            }
            tmax = fmaxf(tmax, __shfl_xor(tmax, 1, 64));
            tmax = fmaxf(tmax, __shfl_xor(tmax, 2, 64));
            tmax = fmaxf(tmax, __shfl_xor(tmax, 4, 64));
            tmax = fmaxf(tmax, __shfl_xor(tmax, 8, 64));
            float mnew = fmaxf(mrow[r], tmax);
            alpha[r] = __expf(mrow[r] - mnew);
            float rsum = 0.f;
            #pragma unroll
            for (int ni = 0; ni < 4; ni++) {
                float e = __expf(p[ni][r] - mnew);
                p[ni][r] = e; rsum += e;
            }
            rsum += __shfl_xor(rsum, 1, 64);
            rsum += __shfl_xor(rsum, 2, 64);
            rsum += __shfl_xor(rsum, 4, 64);
            rsum += __shfl_xor(rsum, 8, 64);
            mrow[r] = mnew;
            lrow[r] = lrow[r] * alpha[r] + rsum;
        }
        #pragma unroll
        for (int ni = 0; ni < 4; ni++) {
            O[ni][0] *= alpha[0]; O[ni][1] *= alpha[1];
            O[ni][2] *= alpha[2]; O[ni][3] *= alpha[3];
            #pragma unroll
            for (int r = 0; r < 4; r++)
                Psw[(q8 * 4 + r) * LDP + ni * 16 + cc] = f2bf(p[ni][r]);   // C-layout -> A-layout via LDS
        }

        // O += P V   (P rows m=cc from wave-private Ps; V^T as B operand)
        #pragma unroll
        for (int ks = 0; ks < 2; ks++) {
            bf16x8 pa = *(const bf16x8*)(Psw + cc * LDP + ks * 32 + q8 * 8);
            #pragma unroll
            for (int ni = 0; ni < 4; ni++) {
                bf16x8 vb = *(const bf16x8*)(Vs + (ni * 16 + cc) * LDP + ks * 32 + q8 * 8);
                O[ni] = __builtin_amdgcn_mfma_f32_16x16x32_bf16(pa, vb, O[ni], 0, 0, 0);
            }
        }
    }

    #pragma unroll
    for (int r = 0; r < 4; r++) {
        int i = i0 + wave * 16 + q8 * 4 + r;
        if (i >= NSEQ) continue;
        float inv = 1.0f / lrow[r];
        #pragma unroll
        for (int ni = 0; ni < 4; ni++)
            o[((size_t)(b * NSEQ + i)) * 768 + h * 64 + ni * 16 + cc] = f2bf(O[ni][r] * inv);
    }
}

extern "C" void kernel_launch(void* const* d_in, const int* in_sizes, int n_in,
                              void* d_out, int out_size, void* d_ws, size_t ws_size,
                              hipStream_t stream)
{
    const float* x     = (const float*)d_in[0];
    const float* sinb  = (const float*)d_in[1];
    const float* cosb  = (const float*)d_in[2];
    const float* ln_g  = (const float*)d_in[3];
    const float* ln_b  = (const float*)d_in[4];
    const float* dw_w  = (const float*)d_in[5];
    const float* pw_w  = (const float*)d_in[6];
    const float* kv_w  = (const float*)d_in[7];
    const float* out_w = (const float*)d_in[8];
    const float* out_b = (const float*)d_in[9];
    (void)in_sizes; (void)n_in; (void)out_size; (void)ws_size;

    u16* ws = (u16*)d_ws;                      // offsets in ushort units
    u16* xn_bf    = ws;                        // 6,297,600 (reused as attn output)
    u16* dwout_bf = ws + 6297600;              // 6,291,456
    u16* q_bf     = ws + 12589056;             // 6,297,600
    u16* k_bf     = ws + 18886656;             // 6,297,600
    u16* v_bf     = ws + 25184256;             // 6,297,600
    u16* Vt       = ws + 31481856;             // 6,389,760 (96*64*1040)
    u16* pw_bf    = ws + 37871616;             // 589,824
    u16* kv_wT    = ws + 38461440;             // 1,179,648
    u16* out_wT   = ws + 39641088;             // 589,824  -> 40,230,912 u16 = 80.5 MB
    float* dwT    = (float*)(ws + 40230912);   // 19,200 fp32
    u16* attn_bf  = xn_bf;                     // xn dead after kv GEMM

    ln_kernel    <<<NTOK, 256, 0, stream>>>(x, ln_g, ln_b, xn_bf);
    cls_q_kernel <<<NBATCH, 256, 0, stream>>>(xn_bf, q_bf);
    dwt_kernel   <<<75, 256, 0, stream>>>(dw_w, dwT);
    dw_kernel    <<<NBATCH * 1024, 256, 0, stream>>>(xn_bf, dwT, dwout_bf);
    convert_kernel<<<2304, 256, 0, stream>>>(pw_w, pw_bf);                       // 768*768
    transpose_f2b<<<dim3(48, 24), dim3(32, 8), 0, stream>>>(kv_w, kv_wT, 768, 1536);
    transpose_f2b<<<dim3(24, 24), dim3(32, 8), 0, stream>>>(out_w, out_wT, 768, 768);
    gemm_bf16<1> <<<dim3(6, 64), 256, 0, stream>>>(dwout_bf, pw_bf, nullptr, q_bf, nullptr, nullptr, 8192);
    gemm_bf16<0> <<<dim3(12, 65), 256, 0, stream>>>(xn_bf, kv_wT, nullptr, k_bf, v_bf, nullptr, NTOK);
    rope_kernel  <<<6144, 256, 0, stream>>>(q_bf, k_bf, sinb, cosb);
    vt_kernel    <<<dim3(33, 2, 96), dim3(32, 8), 0, stream>>>(v_bf, Vt);
    attn_kernel  <<<dim3(17, 96), 256, 0, stream>>>(q_bf, k_bf, Vt, attn_bf);
    gemm_bf16<2> <<<dim3(6, 65), 256, 0, stream>>>(attn_bf, out_wT, out_b, nullptr, nullptr, (float*)d_out, NTOK);
}

// Round 5
// 403.356 us; speedup vs baseline: 2.9546x; 1.1550x over previous
//
#include <hip/hip_runtime.h>
#include <cstddef>

#define NSEQ   1025
#define NBATCH 8
#define NTOK   8200      // 8*1025
#define DIMX   768
#define NHEADS 12
#define DHEAD  64
#define VTP    1040      // Vt row pitch (bf16), 16B-aligned (1040*2=2080=130*16)
#define LDP    72        // LDS row pitch (bf16) for 64-wide K tiles: 144B rows

typedef short bf16x8 __attribute__((ext_vector_type(8)));
typedef float f32x4  __attribute__((ext_vector_type(4)));
typedef unsigned short u16;

__device__ __forceinline__ float bf2f(u16 u) {
    unsigned v = (unsigned)u << 16; float f; __builtin_memcpy(&f, &v, 4); return f;
}
__device__ __forceinline__ u16 f2bf(float f) {
    unsigned u; __builtin_memcpy(&u, &f, 4);
    return (u16)((u + 0x7FFFu + ((u >> 16) & 1u)) >> 16);   // RNE
}

// ---------------- LayerNorm (+ fused cls->q scatter): one block per token ----------------
__launch_bounds__(256)
__global__ void ln_kernel(const float* __restrict__ x, const float* __restrict__ g,
                          const float* __restrict__ bb, u16* __restrict__ xn,
                          u16* __restrict__ qout)
{
    int t = blockIdx.x, tid = threadIdx.x;
    const float* xp = x + (size_t)t * DIMX;
    float v0 = xp[tid], v1 = xp[tid + 256], v2 = xp[tid + 512];
    float s  = v0 + v1 + v2;
    float ss = v0*v0 + v1*v1 + v2*v2;
    for (int off = 32; off > 0; off >>= 1) {
        s  += __shfl_down(s,  off, 64);
        ss += __shfl_down(ss, off, 64);
    }
    __shared__ float red[8];
    __shared__ float stats[2];
    int w = tid >> 6, lane = tid & 63;
    if (lane == 0) { red[w] = s; red[4 + w] = ss; }
    __syncthreads();
    if (tid == 0) {
        float S  = red[0] + red[1] + red[2] + red[3];
        float SS = red[4] + red[5] + red[6] + red[7];
        float mu  = S * (1.0f / DIMX);
        float var = SS * (1.0f / DIMX) - mu * mu;
        stats[0] = mu; stats[1] = rsqrtf(var + 1e-5f);
    }
    __syncthreads();
    float mu = stats[0], rs = stats[1];
    u16 o0 = f2bf((v0 - mu) * rs * g[tid]       + bb[tid]);
    u16 o1 = f2bf((v1 - mu) * rs * g[tid + 256] + bb[tid + 256]);
    u16 o2 = f2bf((v2 - mu) * rs * g[tid + 512] + bb[tid + 512]);
    u16* op = xn + (size_t)t * DIMX;
    op[tid] = o0; op[tid + 256] = o1; op[tid + 512] = o2;
    int bq = t / NSEQ;
    if (t == bq * NSEQ) {   // cls token -> q row 0, head layout
        int c0 = tid, c1 = tid + 256, c2 = tid + 512;
        qout[((size_t)(bq * NHEADS + (c0 >> 6)) * NSEQ) * DHEAD + (c0 & 63)] = o0;
        qout[((size_t)(bq * NHEADS + (c1 >> 6)) * NSEQ) * DHEAD + (c1 & 63)] = o1;
        qout[((size_t)(bq * NHEADS + (c2 >> 6)) * NSEQ) * DHEAD + (c2 & 63)] = o2;
    }
}

// ---------------- fused weight preprocessing ----------------
// blocks [0,75): dw_w (768,25) -> dwT (25,768) fp32
// blocks [75,2379): pw_w fp32 -> pw_bf bf16 (589824 elems)
// blocks [2379,3531): kv_w (768x1536) -> kv_wT (1536x768) bf16   (48x24 tiles)
// blocks [3531,4107): out_w (768x768) -> out_wT (768x768) bf16   (24x24 tiles)
__launch_bounds__(256)
__global__ void preproc_kernel(const float* __restrict__ dw_w, const float* __restrict__ pw_w,
                               const float* __restrict__ kv_w, const float* __restrict__ out_w,
                               float* __restrict__ dwT, u16* __restrict__ pw_bf,
                               u16* __restrict__ kv_wT, u16* __restrict__ out_wT)
{
    __shared__ float tile[32][33];
    int blk = blockIdx.x, tid = threadIdx.x;
    if (blk < 75) {
        int idx = blk * 256 + tid;
        if (idx < 768 * 25) {
            int c = idx / 25, wi = idx % 25;
            dwT[wi * 768 + c] = dw_w[idx];
        }
        return;
    }
    if (blk < 2379) {
        int i = (blk - 75) * 256 + tid;
        pw_bf[i] = f2bf(pw_w[i]);
        return;
    }
    const float* in; u16* out; int R, C, bx, by;
    if (blk < 3531) {
        int t2 = blk - 2379; bx = t2 % 48; by = t2 / 48;
        in = kv_w; out = kv_wT; R = 768; C = 1536;
    } else {
        int t2 = blk - 3531; bx = t2 % 24; by = t2 / 24;
        in = out_w; out = out_wT; R = 768; C = 768;
    }
    int tx = tid & 31, ty = tid >> 5;
    int xg = bx * 32 + tx, y0 = by * 32;
    for (int i = ty; i < 32; i += 8)
        tile[i][tx] = in[(size_t)(y0 + i) * C + xg];
    __syncthreads();
    int xo = by * 32 + tx, yo0 = bx * 32;
    for (int i = ty; i < 32; i += 8)
        out[(size_t)(yo0 + i) * R + xo] = f2bf(tile[tx][i]);
}

// ---------------- depthwise 5x5 conv, vectorized: 8 channels/thread ----------------
__launch_bounds__(256)
__global__ void dw_kernel(const u16* __restrict__ xn, const float* __restrict__ wt,
                          u16* __restrict__ out)
{
    int gid = blockIdx.x * 256 + threadIdx.x;      // 786432 = 8192 px * 96 groups
    int pix = gid / 96, cg = gid - pix * 96;
    int c = cg * 8;
    int b = pix >> 10, p = pix & 1023, y = p >> 5, x0 = p & 31;
    float acc[8] = {};
    for (int dy = 0; dy < 5; dy++) {
        int yy = y + dy - 2;
        if ((unsigned)yy >= 32u) continue;
        for (int dx = 0; dx < 5; dx++) {
            int xx = x0 + dx - 2;
            if ((unsigned)xx >= 32u) continue;
            const u16* ip = xn + ((size_t)(b * NSEQ) + 1 + yy * 32 + xx) * DIMX + c;
            uint4 iv = *(const uint4*)ip;
            const float* wp = wt + (dy * 5 + dx) * DIMX + c;
            float4 w0 = *(const float4*)wp;
            float4 w1 = *(const float4*)(wp + 4);
            acc[0] += bf2f((u16)(iv.x & 0xFFFFu)) * w0.x;
            acc[1] += bf2f((u16)(iv.x >> 16))     * w0.y;
            acc[2] += bf2f((u16)(iv.y & 0xFFFFu)) * w0.z;
            acc[3] += bf2f((u16)(iv.y >> 16))     * w0.w;
            acc[4] += bf2f((u16)(iv.z & 0xFFFFu)) * w1.x;
            acc[5] += bf2f((u16)(iv.z >> 16))     * w1.y;
            acc[6] += bf2f((u16)(iv.w & 0xFFFFu)) * w1.z;
            acc[7] += bf2f((u16)(iv.w >> 16))     * w1.w;
        }
    }
    uint4 ov;
    ov.x = (unsigned)f2bf(acc[0]) | ((unsigned)f2bf(acc[1]) << 16);
    ov.y = (unsigned)f2bf(acc[2]) | ((unsigned)f2bf(acc[3]) << 16);
    ov.z = (unsigned)f2bf(acc[4]) | ((unsigned)f2bf(acc[5]) << 16);
    ov.w = (unsigned)f2bf(acc[6]) | ((unsigned)f2bf(acc[7]) << 16);
    *(uint4*)(out + (size_t)pix * DIMX + c) = ov;
}

// ---------------- bf16 MFMA GEMM: C[M][N] = A[M][768] * Bn^T, Bn = [N][768] (k-major) ----
// MODE 0: kv  -> K/V bf16 head-scatter (N=1536)   MODE 1: pw -> q bf16 head-scatter (n=pix+1)
// MODE 2: out -> fp32 d_out + bias (N=768)
template<int MODE>
__launch_bounds__(256)
__global__ void gemm_bf16(const u16* __restrict__ A, const u16* __restrict__ Bn,
                          const float* __restrict__ bias, u16* __restrict__ Ob0,
                          u16* __restrict__ Ob1, float* __restrict__ Of, int M)
{
    __shared__ u16 As[128 * LDP];
    __shared__ u16 Bs[128 * LDP];
    const int tid  = threadIdx.x;
    const int wave = tid >> 6, lane = tid & 63;
    const int q8 = lane >> 4, cc = lane & 15;
    const int wr = wave >> 1, wc = wave & 1;
    const long r0 = (long)blockIdx.y * 128;
    const int  c0 = blockIdx.x * 128;

    f32x4 acc[4][4] = {};

    for (int k0 = 0; k0 < 768; k0 += 64) {
        // 128 rows x 64 bf16 = 1024 16B-chunks per tile -> 4 passes of 256 threads
        uint4 areg[4], breg[4];
        #pragma unroll
        for (int pass = 0; pass < 4; pass++) {
            int ci = tid + pass * 256;
            int row = ci >> 3, ch = ci & 7;
            long ar = r0 + row;
            areg[pass] = (ar < M) ? *(const uint4*)(A + ar * 768 + k0 + ch * 8)
                                  : make_uint4(0, 0, 0, 0);
            breg[pass] = *(const uint4*)(Bn + (size_t)(c0 + row) * 768 + k0 + ch * 8);
        }
        __syncthreads();
        #pragma unroll
        for (int pass = 0; pass < 4; pass++) {
            int ci = tid + pass * 256;
            int row = ci >> 3, ch = ci & 7;
            *(uint4*)(As + row * LDP + ch * 8) = areg[pass];
            *(uint4*)(Bs + row * LDP + ch * 8) = breg[pass];
        }
        __syncthreads();
        #pragma unroll
        for (int ks = 0; ks < 2; ks++) {
            bf16x8 af[4], bfr[4];
            #pragma unroll
            for (int mi = 0; mi < 4; mi++)
                af[mi] = *(const bf16x8*)(As + (wr * 64 + mi * 16 + cc) * LDP + ks * 32 + q8 * 8);
            #pragma unroll
            for (int ni = 0; ni < 4; ni++)
                bfr[ni] = *(const bf16x8*)(Bs + (wc * 64 + ni * 16 + cc) * LDP + ks * 32 + q8 * 8);
            #pragma unroll
            for (int mi = 0; mi < 4; mi++)
                #pragma unroll
                for (int ni = 0; ni < 4; ni++)
                    acc[mi][ni] = __builtin_amdgcn_mfma_f32_16x16x32_bf16(af[mi], bfr[ni], acc[mi][ni], 0, 0, 0);
        }
    }
    #pragma unroll
    for (int mi = 0; mi < 4; mi++) {
        #pragma unroll
        for (int r = 0; r < 4; r++) {
            long row = r0 + wr * 64 + mi * 16 + q8 * 4 + r;
            if (row >= M) continue;
            int b, n;
            if (MODE == 1) { b = (int)(row >> 10); n = (int)(row & 1023) + 1; }
            else           { b = (int)(row / NSEQ); n = (int)(row % NSEQ); }
            #pragma unroll
            for (int ni = 0; ni < 4; ni++) {
                int col = c0 + wc * 64 + ni * 16 + cc;
                float val = acc[mi][ni][r];
                if (MODE == 0) {
                    if (col < 768)
                        Ob0[((size_t)(b * NHEADS + (col >> 6)) * NSEQ + n) * DHEAD + (col & 63)] = f2bf(val);
                    else {
                        int c2 = col - 768;   // 768 not pow2 — subtract, don't mask
                        Ob1[((size_t)(b * NHEADS + (c2 >> 6)) * NSEQ + n) * DHEAD + (c2 & 63)] = f2bf(val);
                    }
                } else if (MODE == 1) {
                    Ob0[((size_t)(b * NHEADS + (col >> 6)) * NSEQ + n) * DHEAD + (col & 63)] = f2bf(val);
                } else {
                    Of[(size_t)row * 768 + col] = val + bias[col];
                }
            }
        }
    }
}

// ---------------- RoPE on bf16 q,k (first 32 dims/head, n>=1) ----------------
__launch_bounds__(256)
__global__ void rope_kernel(u16* __restrict__ q, u16* __restrict__ k,
                            const float* __restrict__ sinb, const float* __restrict__ cosb)
{
    int idx = blockIdx.x * 256 + threadIdx.x;   // < 96*1024*16
    int pr  = idx & 15;
    int pos = (idx >> 4) & 1023;
    int bh  = idx >> 14;
    float c0 = cosb[pos * 32 + pr * 2], c1 = cosb[pos * 32 + pr * 2 + 1];
    float s0 = sinb[pos * 32 + pr * 2], s1 = sinb[pos * 32 + pr * 2 + 1];
    size_t base = ((size_t)bh * NSEQ + 1 + pos) * DHEAD + pr * 2;
    float q0 = bf2f(q[base]), q1 = bf2f(q[base + 1]);
    float k0 = bf2f(k[base]), k1 = bf2f(k[base + 1]);
    q[base]     = f2bf(q0 * c0 - q1 * s0);
    q[base + 1] = f2bf(q1 * c1 + q0 * s1);
    k[base]     = f2bf(k0 * c0 - k1 * s0);
    k[base + 1] = f2bf(k1 * c1 + k0 * s1);
}

// ---------------- V [bh][1025][64] -> Vt [bh][64][VTP] (zero pad) ----------------
__global__ void vt_kernel(const u16* __restrict__ v, u16* __restrict__ Vt)
{
    __shared__ u16 tile[32][33];
    int bh = blockIdx.z;
    int n0 = blockIdx.x * 32, d0 = blockIdx.y * 32;
    for (int i = threadIdx.y; i < 32; i += 8) {
        int n = n0 + i;
        tile[i][threadIdx.x] = (n < NSEQ) ? v[((size_t)bh * NSEQ + n) * 64 + d0 + threadIdx.x] : (u16)0;
    }
    __syncthreads();
    for (int i = threadIdx.y; i < 32; i += 8) {
        int n = n0 + threadIdx.x;
        if (n < VTP) Vt[((size_t)bh * 64 + d0 + i) * VTP + n] = tile[threadIdx.x][i];
    }
}

// ---------------- flash attention, bf16 MFMA, max-free softmax ----------------
// grid (bh, qtile): linear id = qtile*96 + bh, 96%8==0 -> xcd = bh%8 (all q-tiles of a
// head share an XCD -> K/Vt L2 locality). Logits bounded (|s|<~4 << 88), so exp(s) is
// overflow-safe without the running max; row-sum is deferred to one end-of-kernel reduce.
__launch_bounds__(256)
__global__ void attn_kernel(const u16* __restrict__ q, const u16* __restrict__ k,
                            const u16* __restrict__ Vt, u16* __restrict__ o)
{
    __shared__ u16 Qs[64 * LDP];
    __shared__ u16 Ks[64 * LDP];
    __shared__ u16 Vs[64 * LDP];      // V^T tile: [d][j]
    __shared__ u16 Ps[4 * 16 * LDP];  // per-wave P tile: [row][j]
    const int tid  = threadIdx.x;
    const int wave = tid >> 6, lane = tid & 63;
    const int q8 = lane >> 4, cc = lane & 15;
    const int bh = blockIdx.x;
    const int i0 = blockIdx.y * 64;
    const int b = bh / NHEADS, h = bh % NHEADS;
    const size_t kqbase = (size_t)bh * NSEQ * 64;
    const size_t vtbase = (size_t)bh * 64 * VTP;

    #pragma unroll
    for (int pass = 0; pass < 2; pass++) {
        int ci = tid + pass * 256;
        int row = ci >> 3, ch = ci & 7;
        uint4 val = make_uint4(0, 0, 0, 0);
        if (i0 + row < NSEQ) val = *(const uint4*)(q + kqbase + (size_t)(i0 + row) * 64 + ch * 8);
        *(uint4*)(Qs + row * LDP + ch * 8) = val;
    }

    f32x4 O[4] = {};
    float lsum[4] = {0.f, 0.f, 0.f, 0.f};
    u16* Psw = Ps + wave * 16 * LDP;

    auto tile_body = [&](int j0, bool MASK) {
        __syncthreads();                       // prev iter's K/V reads done (covers Q 1st iter)
        #pragma unroll
        for (int pass = 0; pass < 2; pass++) {
            int ci = tid + pass * 256;
            int row = ci >> 3, ch = ci & 7;
            uint4 kv4 = make_uint4(0, 0, 0, 0);
            if (j0 + row < NSEQ) kv4 = *(const uint4*)(k + kqbase + (size_t)(j0 + row) * 64 + ch * 8);
            *(uint4*)(Ks + row * LDP + ch * 8) = kv4;
            uint4 vv4 = make_uint4(0, 0, 0, 0);
            if (j0 + ch * 8 < VTP) vv4 = *(const uint4*)(Vt + vtbase + (size_t)row * VTP + j0 + ch * 8);
            *(uint4*)(Vs + row * LDP + ch * 8) = vv4;
        }
        __syncthreads();

        // S = Q K^T : wave's 16 rows x 64 cols in 4 frags
        f32x4 sf[4] = {};
        #pragma unroll
        for (int ks = 0; ks < 2; ks++) {
            bf16x8 aq = *(const bf16x8*)(Qs + (wave * 16 + cc) * LDP + ks * 32 + q8 * 8);
            #pragma unroll
            for (int ni = 0; ni < 4; ni++) {
                bf16x8 bk = *(const bf16x8*)(Ks + (ni * 16 + cc) * LDP + ks * 32 + q8 * 8);
                sf[ni] = __builtin_amdgcn_mfma_f32_16x16x32_bf16(aq, bk, sf[ni], 0, 0, 0);
            }
        }

        // max-free softmax: p = exp(s/8); accumulate per-lane partial row sums
        #pragma unroll
        for (int ni = 0; ni < 4; ni++) {
            #pragma unroll
            for (int r = 0; r < 4; r++) {
                float p = __expf(sf[ni][r] * 0.125f);
                if (MASK && (j0 + ni * 16 + cc >= NSEQ)) p = 0.f;
                lsum[r] += p;
                unsigned u; __builtin_memcpy(&u, &p, 4);
                Psw[(q8 * 4 + r) * LDP + ni * 16 + cc] = (u16)((u + 0x8000u) >> 16);  // fast round
            }
        }

        // O += P V   (P rows m=cc from wave-private Ps; V^T as B operand)
        #pragma unroll
        for (int ks = 0; ks < 2; ks++) {
            bf16x8 pa = *(const bf16x8*)(Psw + cc * LDP + ks * 32 + q8 * 8);
            #pragma unroll
            for (int ni = 0; ni < 4; ni++) {
                bf16x8 vb = *(const bf16x8*)(Vs + (ni * 16 + cc) * LDP + ks * 32 + q8 * 8);
                O[ni] = __builtin_amdgcn_mfma_f32_16x16x32_bf16(pa, vb, O[ni], 0, 0, 0);
            }
        }
    };

    for (int jt = 0; jt < 16; jt++) tile_body(jt * 64, false);   // j<=1023 always valid
    tile_body(1024, true);                                        // masked tail tile

    #pragma unroll
    for (int r = 0; r < 4; r++) {
        lsum[r] += __shfl_xor(lsum[r], 1, 64);
        lsum[r] += __shfl_xor(lsum[r], 2, 64);
        lsum[r] += __shfl_xor(lsum[r], 4, 64);
        lsum[r] += __shfl_xor(lsum[r], 8, 64);
    }
    #pragma unroll
    for (int r = 0; r < 4; r++) {
        int i = i0 + wave * 16 + q8 * 4 + r;
        if (i >= NSEQ) continue;
        float inv = 1.0f / lsum[r];
        #pragma unroll
        for (int ni = 0; ni < 4; ni++)
            o[((size_t)(b * NSEQ + i)) * 768 + h * 64 + ni * 16 + cc] = f2bf(O[ni][r] * inv);
    }
}

extern "C" void kernel_launch(void* const* d_in, const int* in_sizes, int n_in,
                              void* d_out, int out_size, void* d_ws, size_t ws_size,
                              hipStream_t stream)
{
    const float* x     = (const float*)d_in[0];
    const float* sinb  = (const float*)d_in[1];
    const float* cosb  = (const float*)d_in[2];
    const float* ln_g  = (const float*)d_in[3];
    const float* ln_b  = (const float*)d_in[4];
    const float* dw_w  = (const float*)d_in[5];
    const float* pw_w  = (const float*)d_in[6];
    const float* kv_w  = (const float*)d_in[7];
    const float* out_w = (const float*)d_in[8];
    const float* out_b = (const float*)d_in[9];
    (void)in_sizes; (void)n_in; (void)out_size; (void)ws_size;

    u16* ws = (u16*)d_ws;                      // offsets in ushort units
    u16* xn_bf    = ws;                        // 6,297,600 (reused as attn output)
    u16* dwout_bf = ws + 6297600;              // 6,291,456
    u16* q_bf     = ws + 12589056;             // 6,297,600
    u16* k_bf     = ws + 18886656;             // 6,297,600
    u16* v_bf     = ws + 25184256;             // 6,297,600
    u16* Vt       = ws + 31481856;             // 6,389,760 (96*64*1040)
    u16* pw_bf    = ws + 37871616;             // 589,824
    u16* kv_wT    = ws + 38461440;             // 1,179,648
    u16* out_wT   = ws + 39641088;             // 589,824  -> 40,230,912 u16 = 80.5 MB
    float* dwT    = (float*)(ws + 40230912);   // 19,200 fp32
    u16* attn_bf  = xn_bf;                     // xn dead after kv GEMM

    ln_kernel      <<<NTOK, 256, 0, stream>>>(x, ln_g, ln_b, xn_bf, q_bf);
    preproc_kernel <<<4107, 256, 0, stream>>>(dw_w, pw_w, kv_w, out_w, dwT, pw_bf, kv_wT, out_wT);
    dw_kernel      <<<3072, 256, 0, stream>>>(xn_bf, dwT, dwout_bf);
    gemm_bf16<1>   <<<dim3(6, 64), 256, 0, stream>>>(dwout_bf, pw_bf, nullptr, q_bf, nullptr, nullptr, 8192);
    gemm_bf16<0>   <<<dim3(12, 65), 256, 0, stream>>>(xn_bf, kv_wT, nullptr, k_bf, v_bf, nullptr, NTOK);
    rope_kernel    <<<6144, 256, 0, stream>>>(q_bf, k_bf, sinb, cosb);
    vt_kernel      <<<dim3(33, 2, 96), dim3(32, 8), 0, stream>>>(v_bf, Vt);
    attn_kernel    <<<dim3(96, 17), 256, 0, stream>>>(q_bf, k_bf, Vt, attn_bf);
    gemm_bf16<2>   <<<dim3(6, 65), 256, 0, stream>>>(attn_bf, out_wT, out_b, nullptr, nullptr, (float*)d_out, NTOK);
}

// Round 6
// 306.414 us; speedup vs baseline: 3.8894x; 1.3164x over previous
//
#include <hip/hip_runtime.h>
#include <cstddef>

#define NSEQ   1025
#define NBATCH 8
#define NTOK   8200      // 8*1025
#define DIMX   768
#define NHEADS 12
#define DHEAD  64
#define VTP    1040      // Vt row pitch (bf16), 16B-aligned
#define LDP    72        // LDS row pitch (bf16) for attn 64-wide tiles
#define CP     136       // epilogue repack pitch (bf16): 128+8, 1.58x-conflict b16 writes

typedef short bf16x8 __attribute__((ext_vector_type(8)));
typedef float f32x4  __attribute__((ext_vector_type(4)));
typedef unsigned short u16;

__device__ __forceinline__ float bf2f(u16 u) {
    unsigned v = (unsigned)u << 16; float f; __builtin_memcpy(&f, &v, 4); return f;
}
__device__ __forceinline__ u16 f2bf(float f) {
    unsigned u; __builtin_memcpy(&u, &f, 4);
    return (u16)((u + 0x7FFFu + ((u >> 16) & 1u)) >> 16);   // RNE
}

// async 16B global->LDS (dest = wave-uniform base + lane*16)
__device__ __forceinline__ void gl2lds16(const u16* g, u16* l) {
    __builtin_amdgcn_global_load_lds((__attribute__((address_space(1))) void*)g,
                                     (__attribute__((address_space(3))) void*)l, 16, 0, 0);
}

// ---------------- LayerNorm (+ fused cls->q scatter): one block per token ----------------
__launch_bounds__(256)
__global__ void ln_kernel(const float* __restrict__ x, const float* __restrict__ g,
                          const float* __restrict__ bb, u16* __restrict__ xn,
                          u16* __restrict__ qout)
{
    int t = blockIdx.x, tid = threadIdx.x;
    const float* xp = x + (size_t)t * DIMX;
    float v0 = xp[tid], v1 = xp[tid + 256], v2 = xp[tid + 512];
    float s  = v0 + v1 + v2;
    float ss = v0*v0 + v1*v1 + v2*v2;
    for (int off = 32; off > 0; off >>= 1) {
        s  += __shfl_down(s,  off, 64);
        ss += __shfl_down(ss, off, 64);
    }
    __shared__ float red[8];
    __shared__ float stats[2];
    int w = tid >> 6, lane = tid & 63;
    if (lane == 0) { red[w] = s; red[4 + w] = ss; }
    __syncthreads();
    if (tid == 0) {
        float S  = red[0] + red[1] + red[2] + red[3];
        float SS = red[4] + red[5] + red[6] + red[7];
        float mu  = S * (1.0f / DIMX);
        float var = SS * (1.0f / DIMX) - mu * mu;
        stats[0] = mu; stats[1] = rsqrtf(var + 1e-5f);
    }
    __syncthreads();
    float mu = stats[0], rs = stats[1];
    u16 o0 = f2bf((v0 - mu) * rs * g[tid]       + bb[tid]);
    u16 o1 = f2bf((v1 - mu) * rs * g[tid + 256] + bb[tid + 256]);
    u16 o2 = f2bf((v2 - mu) * rs * g[tid + 512] + bb[tid + 512]);
    u16* op = xn + (size_t)t * DIMX;
    op[tid] = o0; op[tid + 256] = o1; op[tid + 512] = o2;
    int bq = t / NSEQ;
    if (t == bq * NSEQ) {   // cls token -> q row 0, head layout
        int c0 = tid, c1 = tid + 256, c2 = tid + 512;
        qout[((size_t)(bq * NHEADS + (c0 >> 6)) * NSEQ) * DHEAD + (c0 & 63)] = o0;
        qout[((size_t)(bq * NHEADS + (c1 >> 6)) * NSEQ) * DHEAD + (c1 & 63)] = o1;
        qout[((size_t)(bq * NHEADS + (c2 >> 6)) * NSEQ) * DHEAD + (c2 & 63)] = o2;
    }
}

// ---------------- fused weight preprocessing ----------------
__launch_bounds__(256)
__global__ void preproc_kernel(const float* __restrict__ dw_w, const float* __restrict__ pw_w,
                               const float* __restrict__ kv_w, const float* __restrict__ out_w,
                               float* __restrict__ dwT, u16* __restrict__ pw_bf,
                               u16* __restrict__ kv_wT, u16* __restrict__ out_wT)
{
    __shared__ float tile[32][33];
    int blk = blockIdx.x, tid = threadIdx.x;
    if (blk < 75) {
        int idx = blk * 256 + tid;
        if (idx < 768 * 25) {
            int c = idx / 25, wi = idx % 25;
            dwT[wi * 768 + c] = dw_w[idx];
        }
        return;
    }
    if (blk < 2379) {
        int i = (blk - 75) * 256 + tid;
        pw_bf[i] = f2bf(pw_w[i]);
        return;
    }
    const float* in; u16* out; int R, C, bx, by;
    if (blk < 3531) {
        int t2 = blk - 2379; bx = t2 % 48; by = t2 / 48;
        in = kv_w; out = kv_wT; R = 768; C = 1536;
    } else {
        int t2 = blk - 3531; bx = t2 % 24; by = t2 / 24;
        in = out_w; out = out_wT; R = 768; C = 768;
    }
    int tx = tid & 31, ty = tid >> 5;
    int xg = bx * 32 + tx, y0 = by * 32;
    for (int i = ty; i < 32; i += 8)
        tile[i][tx] = in[(size_t)(y0 + i) * C + xg];
    __syncthreads();
    int xo = by * 32 + tx, yo0 = bx * 32;
    for (int i = ty; i < 32; i += 8)
        out[(size_t)(yo0 + i) * R + xo] = f2bf(tile[tx][i]);
}

// ---------------- depthwise 5x5 conv, vectorized: 8 channels/thread ----------------
__launch_bounds__(256)
__global__ void dw_kernel(const u16* __restrict__ xn, const float* __restrict__ wt,
                          u16* __restrict__ out)
{
    int gid = blockIdx.x * 256 + threadIdx.x;      // 786432 = 8192 px * 96 groups
    int pix = gid / 96, cg = gid - pix * 96;
    int c = cg * 8;
    int b = pix >> 10, p = pix & 1023, y = p >> 5, x0 = p & 31;
    float acc[8] = {};
    for (int dy = 0; dy < 5; dy++) {
        int yy = y + dy - 2;
        if ((unsigned)yy >= 32u) continue;
        for (int dx = 0; dx < 5; dx++) {
            int xx = x0 + dx - 2;
            if ((unsigned)xx >= 32u) continue;
            const u16* ip = xn + ((size_t)(b * NSEQ) + 1 + yy * 32 + xx) * DIMX + c;
            uint4 iv = *(const uint4*)ip;
            const float* wp = wt + (dy * 5 + dx) * DIMX + c;
            float4 w0 = *(const float4*)wp;
            float4 w1 = *(const float4*)(wp + 4);
            acc[0] += bf2f((u16)(iv.x & 0xFFFFu)) * w0.x;
            acc[1] += bf2f((u16)(iv.x >> 16))     * w0.y;
            acc[2] += bf2f((u16)(iv.y & 0xFFFFu)) * w0.z;
            acc[3] += bf2f((u16)(iv.y >> 16))     * w0.w;
            acc[4] += bf2f((u16)(iv.z & 0xFFFFu)) * w1.x;
            acc[5] += bf2f((u16)(iv.z >> 16))     * w1.y;
            acc[6] += bf2f((u16)(iv.w & 0xFFFFu)) * w1.z;
            acc[7] += bf2f((u16)(iv.w >> 16))     * w1.w;
        }
    }
    uint4 ov;
    ov.x = (unsigned)f2bf(acc[0]) | ((unsigned)f2bf(acc[1]) << 16);
    ov.y = (unsigned)f2bf(acc[2]) | ((unsigned)f2bf(acc[3]) << 16);
    ov.z = (unsigned)f2bf(acc[4]) | ((unsigned)f2bf(acc[5]) << 16);
    ov.w = (unsigned)f2bf(acc[6]) | ((unsigned)f2bf(acc[7]) << 16);
    *(uint4*)(out + (size_t)pix * DIMX + c) = ov;
}

// ---------------- bf16 MFMA GEMM, m97-style: async LDS staging + XOR swizzle ----------
// C[M][N] = A[M][768] * Bn^T (Bn k-major [N][768]). 128x128 tile, BK=64, 4 waves 2x2.
// LDS pitch 64 (contiguous rows for global_load_lds); chunk swizzle cs^=(row&7) makes
// fragment ds_read_b128 2-lanes/bank (free). Epilogue (modes 0/1): acc -> LDS (pitch 136)
// -> coalesced uint4 head-layout stores (fixes R5's 4.8x write amplification).
// MODE 0: kv -> K/V bf16 head-scatter (N=1536)  MODE 1: pw -> q (n=pix+1)  MODE 2: fp32+bias
template<int MODE>
__launch_bounds__(256)
__global__ void gemm_bf16(const u16* __restrict__ A, const u16* __restrict__ Bn,
                          const float* __restrict__ bias, u16* __restrict__ Ob0,
                          u16* __restrict__ Ob1, float* __restrict__ Of, int M)
{
    __shared__ u16 smem[128 * CP];          // 34816 B; aliases As(16KB)+Bs(16KB) then Ct
    u16* As = smem;
    u16* Bs = smem + 8192;
    const int tid  = threadIdx.x;
    const int wave = tid >> 6, lane = tid & 63;
    const int q8 = lane >> 4, cc = lane & 15;
    const int wr = wave >> 1, wc = wave & 1;
    const long r0 = (long)blockIdx.y * 128;
    const int  c0 = blockIdx.x * 128;

    f32x4 acc[4][4] = {};

    for (int k0 = 0; k0 < 768; k0 += 64) {
        __syncthreads();                    // prior iter's fragment reads done
        #pragma unroll
        for (int p = 0; p < 4; p++) {
            int chunk = wave * 256 + p * 64 + lane;      // 1024 chunks per 128x64 tile
            int row = chunk >> 3, cs = chunk & 7;
            int src = cs ^ (row & 7);                     // swizzled source chunk
            const u16* ga = A  + (size_t)(r0 + row) * 768 + k0 + src * 8;
            const u16* gb = Bn + (size_t)(c0 + row) * 768 + k0 + src * 8;
            u16* la = As + (size_t)(wave * 256 + p * 64) * 8;   // wave-uniform base
            u16* lb = Bs + (size_t)(wave * 256 + p * 64) * 8;
            gl2lds16(ga, la);
            gl2lds16(gb, lb);
        }
        __syncthreads();                    // drains vmcnt -> LDS valid
        #pragma unroll
        for (int ks = 0; ks < 2; ks++) {
            const int chsw = (((ks * 4 + q8) ^ (cc & 7)) * 8);
            bf16x8 af[4], bfr[4];
            #pragma unroll
            for (int mi = 0; mi < 4; mi++)
                af[mi] = *(const bf16x8*)(As + (wr * 64 + mi * 16 + cc) * 64 + chsw);
            #pragma unroll
            for (int ni = 0; ni < 4; ni++)
                bfr[ni] = *(const bf16x8*)(Bs + (wc * 64 + ni * 16 + cc) * 64 + chsw);
            #pragma unroll
            for (int mi = 0; mi < 4; mi++)
                #pragma unroll
                for (int ni = 0; ni < 4; ni++)
                    acc[mi][ni] = __builtin_amdgcn_mfma_f32_16x16x32_bf16(af[mi], bfr[ni], acc[mi][ni], 0, 0, 0);
        }
    }

    if (MODE == 2) {
        #pragma unroll
        for (int mi = 0; mi < 4; mi++) {
            #pragma unroll
            for (int r = 0; r < 4; r++) {
                long row = r0 + wr * 64 + mi * 16 + q8 * 4 + r;
                if (row >= M) continue;
                #pragma unroll
                for (int ni = 0; ni < 4; ni++) {
                    int col = c0 + wc * 64 + ni * 16 + cc;
                    Of[(size_t)row * 768 + col] = acc[mi][ni][r] + bias[col];
                }
            }
        }
        return;
    }

    // modes 0/1: repack through LDS, then coalesced 16B stores in head layout
    __syncthreads();                        // all fragment reads done; reuse smem as Ct
    #pragma unroll
    for (int mi = 0; mi < 4; mi++)
        #pragma unroll
        for (int r = 0; r < 4; r++) {
            int lr = wr * 64 + mi * 16 + q8 * 4 + r;
            #pragma unroll
            for (int ni = 0; ni < 4; ni++)
                smem[lr * CP + wc * 64 + ni * 16 + cc] = f2bf(acc[mi][ni][r]);
        }
    __syncthreads();
    #pragma unroll
    for (int p = 0; p < 8; p++) {
        int id = p * 256 + tid;             // 2048 uint4 chunks (128 rows x 16)
        int row = id >> 4, c8 = (id & 15) * 8;
        long grow = r0 + row;
        if (grow >= M) continue;
        uint4 val = *(const uint4*)(smem + row * CP + c8);
        int b, n;
        if (MODE == 1) { b = (int)(grow >> 10); n = (int)(grow & 1023) + 1; }
        else           { b = (int)(grow / NSEQ); n = (int)(grow % NSEQ); }
        int col = c0 + c8;
        u16* dst; int c2;
        if (MODE == 0 && col >= 768) { dst = Ob1; c2 = col - 768; }   // 768 not pow2: subtract
        else                         { dst = Ob0; c2 = col; }
        *(uint4*)(dst + ((size_t)(b * NHEADS + (c2 >> 6)) * NSEQ + n) * DHEAD + (c2 & 63)) = val;
    }
}

// ---------------- RoPE on bf16 q,k (first 32 dims/head, n>=1) ----------------
__launch_bounds__(256)
__global__ void rope_kernel(u16* __restrict__ q, u16* __restrict__ k,
                            const float* __restrict__ sinb, const float* __restrict__ cosb)
{
    int idx = blockIdx.x * 256 + threadIdx.x;   // < 96*1024*16
    int pr  = idx & 15;
    int pos = (idx >> 4) & 1023;
    int bh  = idx >> 14;
    float c0 = cosb[pos * 32 + pr * 2], c1 = cosb[pos * 32 + pr * 2 + 1];
    float s0 = sinb[pos * 32 + pr * 2], s1 = sinb[pos * 32 + pr * 2 + 1];
    size_t base = ((size_t)bh * NSEQ + 1 + pos) * DHEAD + pr * 2;
    float q0 = bf2f(q[base]), q1 = bf2f(q[base + 1]);
    float k0 = bf2f(k[base]), k1 = bf2f(k[base + 1]);
    q[base]     = f2bf(q0 * c0 - q1 * s0);
    q[base + 1] = f2bf(q1 * c1 + q0 * s1);
    k[base]     = f2bf(k0 * c0 - k1 * s0);
    k[base + 1] = f2bf(k1 * c1 + k0 * s1);
}

// ---------------- V [bh][1025][64] -> Vt [bh][64][VTP] (zero pad) ----------------
__global__ void vt_kernel(const u16* __restrict__ v, u16* __restrict__ Vt)
{
    __shared__ u16 tile[32][33];
    int bh = blockIdx.z;
    int n0 = blockIdx.x * 32, d0 = blockIdx.y * 32;
    for (int i = threadIdx.y; i < 32; i += 8) {
        int n = n0 + i;
        tile[i][threadIdx.x] = (n < NSEQ) ? v[((size_t)bh * NSEQ + n) * 64 + d0 + threadIdx.x] : (u16)0;
    }
    __syncthreads();
    for (int i = threadIdx.y; i < 32; i += 8) {
        int n = n0 + threadIdx.x;
        if (n < VTP) Vt[((size_t)bh * 64 + d0 + i) * VTP + n] = tile[threadIdx.x][i];
    }
}

// ---------------- flash attention, bf16 MFMA, max-free softmax ----------------
__launch_bounds__(256)
__global__ void attn_kernel(const u16* __restrict__ q, const u16* __restrict__ k,
                            const u16* __restrict__ Vt, u16* __restrict__ o)
{
    __shared__ u16 Qs[64 * LDP];
    __shared__ u16 Ks[64 * LDP];
    __shared__ u16 Vs[64 * LDP];      // V^T tile: [d][j]
    __shared__ u16 Ps[4 * 16 * LDP];  // per-wave P tile: [row][j]
    const int tid  = threadIdx.x;
    const int wave = tid >> 6, lane = tid & 63;
    const int q8 = lane >> 4, cc = lane & 15;
    const int bh = blockIdx.x;
    const int i0 = blockIdx.y * 64;
    const int b = bh / NHEADS, h = bh % NHEADS;
    const size_t kqbase = (size_t)bh * NSEQ * 64;
    const size_t vtbase = (size_t)bh * 64 * VTP;

    #pragma unroll
    for (int pass = 0; pass < 2; pass++) {
        int ci = tid + pass * 256;
        int row = ci >> 3, ch = ci & 7;
        uint4 val = make_uint4(0, 0, 0, 0);
        if (i0 + row < NSEQ) val = *(const uint4*)(q + kqbase + (size_t)(i0 + row) * 64 + ch * 8);
        *(uint4*)(Qs + row * LDP + ch * 8) = val;
    }

    f32x4 O[4] = {};
    float lsum[4] = {0.f, 0.f, 0.f, 0.f};
    u16* Psw = Ps + wave * 16 * LDP;

    auto tile_body = [&](int j0, bool MASK) {
        __syncthreads();
        #pragma unroll
        for (int pass = 0; pass < 2; pass++) {
            int ci = tid + pass * 256;
            int row = ci >> 3, ch = ci & 7;
            uint4 kv4 = make_uint4(0, 0, 0, 0);
            if (j0 + row < NSEQ) kv4 = *(const uint4*)(k + kqbase + (size_t)(j0 + row) * 64 + ch * 8);
            *(uint4*)(Ks + row * LDP + ch * 8) = kv4;
            uint4 vv4 = make_uint4(0, 0, 0, 0);
            if (j0 + ch * 8 < VTP) vv4 = *(const uint4*)(Vt + vtbase + (size_t)row * VTP + j0 + ch * 8);
            *(uint4*)(Vs + row * LDP + ch * 8) = vv4;
        }
        __syncthreads();

        f32x4 sf[4] = {};
        #pragma unroll
        for (int ks = 0; ks < 2; ks++) {
            bf16x8 aq = *(const bf16x8*)(Qs + (wave * 16 + cc) * LDP + ks * 32 + q8 * 8);
            #pragma unroll
            for (int ni = 0; ni < 4; ni++) {
                bf16x8 bk = *(const bf16x8*)(Ks + (ni * 16 + cc) * LDP + ks * 32 + q8 * 8);
                sf[ni] = __builtin_amdgcn_mfma_f32_16x16x32_bf16(aq, bk, sf[ni], 0, 0, 0);
            }
        }

        #pragma unroll
        for (int ni = 0; ni < 4; ni++) {
            #pragma unroll
            for (int r = 0; r < 4; r++) {
                float p = __expf(sf[ni][r] * 0.125f);
                if (MASK && (j0 + ni * 16 + cc >= NSEQ)) p = 0.f;
                lsum[r] += p;
                unsigned u; __builtin_memcpy(&u, &p, 4);
                Psw[(q8 * 4 + r) * LDP + ni * 16 + cc] = (u16)((u + 0x8000u) >> 16);  // fast round
            }
        }

        #pragma unroll
        for (int ks = 0; ks < 2; ks++) {
            bf16x8 pa = *(const bf16x8*)(Psw + cc * LDP + ks * 32 + q8 * 8);
            #pragma unroll
            for (int ni = 0; ni < 4; ni++) {
                bf16x8 vb = *(const bf16x8*)(Vs + (ni * 16 + cc) * LDP + ks * 32 + q8 * 8);
                O[ni] = __builtin_amdgcn_mfma_f32_16x16x32_bf16(pa, vb, O[ni], 0, 0, 0);
            }
        }
    };

    for (int jt = 0; jt < 16; jt++) tile_body(jt * 64, false);
    tile_body(1024, true);

    #pragma unroll
    for (int r = 0; r < 4; r++) {
        lsum[r] += __shfl_xor(lsum[r], 1, 64);
        lsum[r] += __shfl_xor(lsum[r], 2, 64);
        lsum[r] += __shfl_xor(lsum[r], 4, 64);
        lsum[r] += __shfl_xor(lsum[r], 8, 64);
    }
    #pragma unroll
    for (int r = 0; r < 4; r++) {
        int i = i0 + wave * 16 + q8 * 4 + r;
        if (i >= NSEQ) continue;
        float inv = 1.0f / lsum[r];
        #pragma unroll
        for (int ni = 0; ni < 4; ni++)
            o[((size_t)(b * NSEQ + i)) * 768 + h * 64 + ni * 16 + cc] = f2bf(O[ni][r] * inv);
    }
}

extern "C" void kernel_launch(void* const* d_in, const int* in_sizes, int n_in,
                              void* d_out, int out_size, void* d_ws, size_t ws_size,
                              hipStream_t stream)
{
    const float* x     = (const float*)d_in[0];
    const float* sinb  = (const float*)d_in[1];
    const float* cosb  = (const float*)d_in[2];
    const float* ln_g  = (const float*)d_in[3];
    const float* ln_b  = (const float*)d_in[4];
    const float* dw_w  = (const float*)d_in[5];
    const float* pw_w  = (const float*)d_in[6];
    const float* kv_w  = (const float*)d_in[7];
    const float* out_w = (const float*)d_in[8];
    const float* out_b = (const float*)d_in[9];
    (void)in_sizes; (void)n_in; (void)out_size; (void)ws_size;

    u16* ws = (u16*)d_ws;                      // offsets in ushort units
    u16* xn_bf    = ws;                        // 6,297,600 (reused as attn output)
    u16* dwout_bf = ws + 6297600;              // 6,291,456
    u16* q_bf     = ws + 12589056;             // 6,297,600
    u16* k_bf     = ws + 18886656;             // 6,297,600
    u16* v_bf     = ws + 25184256;             // 6,297,600
    u16* Vt       = ws + 31481856;             // 6,389,760 (96*64*1040)
    u16* pw_bf    = ws + 37871616;             // 589,824
    u16* kv_wT    = ws + 38461440;             // 1,179,648
    u16* out_wT   = ws + 39641088;             // 589,824  -> 40,230,912 u16 = 80.5 MB
    float* dwT    = (float*)(ws + 40230912);   // 19,200 fp32
    u16* attn_bf  = xn_bf;                     // xn dead after kv GEMM

    ln_kernel      <<<NTOK, 256, 0, stream>>>(x, ln_g, ln_b, xn_bf, q_bf);
    preproc_kernel <<<4107, 256, 0, stream>>>(dw_w, pw_w, kv_w, out_w, dwT, pw_bf, kv_wT, out_wT);
    dw_kernel      <<<3072, 256, 0, stream>>>(xn_bf, dwT, dwout_bf);
    gemm_bf16<1>   <<<dim3(6, 64), 256, 0, stream>>>(dwout_bf, pw_bf, nullptr, q_bf, nullptr, nullptr, 8192);
    gemm_bf16<0>   <<<dim3(12, 65), 256, 0, stream>>>(xn_bf, kv_wT, nullptr, k_bf, v_bf, nullptr, NTOK);
    rope_kernel    <<<6144, 256, 0, stream>>>(q_bf, k_bf, sinb, cosb);
    vt_kernel      <<<dim3(33, 2, 96), dim3(32, 8), 0, stream>>>(v_bf, Vt);
    attn_kernel    <<<dim3(96, 17), 256, 0, stream>>>(q_bf, k_bf, Vt, attn_bf);
    gemm_bf16<2>   <<<dim3(6, 65), 256, 0, stream>>>(attn_bf, out_wT, out_b, nullptr, nullptr, (float*)d_out, NTOK);
}